// Round 2
// baseline (503.703 us; speedup 1.0000x reference)
//
#include <hip/hip_runtime.h>
#include <hip/hip_bf16.h>
#include <hip/hip_fp16.h>
#include <math.h>

// Problem dims (fixed by reference)
#define B_  32
#define T_  512
#define F_  4096
#define H_  128
#define G4H 512           // 4*H
#define NCLS 3            // NUM_CLASSES + 1
#define M_  (B_ * T_)     // 16384 rows
#define KSTEPS 128        // F_/32

typedef _Float16 f16x8 __attribute__((ext_vector_type(8)));
typedef _Float16 f16x4 __attribute__((ext_vector_type(4)));
typedef float    f32x4 __attribute__((ext_vector_type(4)));

// async global->LDS, 16B per lane; LDS dest is wave-uniform base + lane*16
__device__ __forceinline__ void gl_lds16(const _Float16* g, _Float16* l) {
    __builtin_amdgcn_global_load_lds(
        (const __attribute__((address_space(1))) void*)(g),
        (__attribute__((address_space(3))) void*)(l), 16, 0, 0);
}

// ---------------------------------------------------------------------------
// Kernel 0b: Wk [F,4H] fp32 -> btK fp16, K-MAJOR tiles with baked-in group
// swizzle: group g (8 halves) of column n stored at half-offset
//   n*32 + ((g ^ ((n>>1)&3)) << 3)
// so gemm's ds_read_b128 B-fragment reads are bank-conflict-free (2-way).
// ---------------------------------------------------------------------------
__global__ __launch_bounds__(256) void cvt_wkT(
    const float* __restrict__ Wk, _Float16* __restrict__ btK)
{
    __shared__ float ls[64][65];
    const int k0 = blockIdx.x * 64;
    const int n0 = blockIdx.y * 64;
    const int tid = threadIdx.x;

    {
        int r  = tid >> 4;
        int c4 = (tid & 15) * 4;
        #pragma unroll
        for (int p = 0; p < 4; ++p) {
            float4 v = *reinterpret_cast<const float4*>(
                &Wk[(size_t)(k0 + r + p * 16) * G4H + n0 + c4]);
            ls[r + p * 16][c4 + 0] = v.x;
            ls[r + p * 16][c4 + 1] = v.y;
            ls[r + p * 16][c4 + 2] = v.z;
            ls[r + p * 16][c4 + 3] = v.w;
        }
    }
    __syncthreads();
    {
        int rn = tid >> 2;            // n within tile 0..63
        int ck = (tid & 3) * 16;      // k within tile 0,16,32,48
        f16x8 h0, h1;
        #pragma unroll
        for (int j = 0; j < 8; ++j) {
            h0[j] = (_Float16)ls[ck + j][rn];
            h1[j] = (_Float16)ls[ck + 8 + j][rn];
        }
        const int n    = n0 + rn;
        const int kg   = k0 + ck;
        const int kblk = kg >> 5;
        const int kk   = kg & 31;           // 0 or 16
        const int g0   = kk >> 3;           // 0 or 2
        const int sw   = (n >> 1) & 3;
        _Float16* base = btK + (size_t)kblk * (512 * 32) + (size_t)n * 32;
        *reinterpret_cast<f16x8*>(base + ((g0 ^ sw) << 3))       = h0;
        *reinterpret_cast<f16x8*>(base + (((g0 + 1) ^ sw) << 3)) = h1;
    }
}

// ---------------------------------------------------------------------------
// Kernel 0c: Wr [H,4H] fp32 -> wrT [4H,H] fp16 (transpose). grid (2, 8).
// ---------------------------------------------------------------------------
__global__ __launch_bounds__(256) void cvt_wrT(
    const float* __restrict__ Wr, _Float16* __restrict__ wrT)
{
    __shared__ float ls[64][65];
    const int k0 = blockIdx.x * 64;
    const int n0 = blockIdx.y * 64;
    const int tid = threadIdx.x;
    {
        int r  = tid >> 4;
        int c4 = (tid & 15) * 4;
        #pragma unroll
        for (int p = 0; p < 4; ++p) {
            float4 v = *reinterpret_cast<const float4*>(
                &Wr[(size_t)(k0 + r + p * 16) * G4H + n0 + c4]);
            ls[r + p * 16][c4 + 0] = v.x;
            ls[r + p * 16][c4 + 1] = v.y;
            ls[r + p * 16][c4 + 2] = v.z;
            ls[r + p * 16][c4 + 3] = v.w;
        }
    }
    __syncthreads();
    {
        int rn = tid >> 2;
        int ck = (tid & 3) * 16;
        f16x8 h0, h1;
        #pragma unroll
        for (int j = 0; j < 8; ++j) {
            h0[j] = (_Float16)ls[ck + j][rn];
            h1[j] = (_Float16)ls[ck + 8 + j][rn];
        }
        _Float16* dst = &wrT[(size_t)(n0 + rn) * H_ + k0 + ck];
        *reinterpret_cast<f16x8*>(dst)     = h0;
        *reinterpret_cast<f16x8*>(dst + 8) = h1;
    }
}

// Light producer-consumer barrier: LDS-drain only, no vmcnt drain.
__device__ __forceinline__ void lds_barrier() {
    asm volatile("s_waitcnt lgkmcnt(0)" ::: "memory");
    __builtin_amdgcn_s_barrier();
    asm volatile("" ::: "memory");
}

// ---------------------------------------------------------------------------
// Kernel 1: FUSED z = f16(x) @ Wk + b. (unchanged from R16)
// ---------------------------------------------------------------------------
__global__ __launch_bounds__(512, 4) void gemm_fused(
    const float* __restrict__ x, const _Float16* __restrict__ btK,
    const float* __restrict__ bias, float* __restrict__ z)
{
    __shared__ __align__(16) _Float16 As[3][64 * 32];    // 12 KB
    __shared__ __align__(16) _Float16 Bs[3][256 * 32];   // 48 KB

    const int tid = threadIdx.x;
    const int w   = tid >> 6;
    const int l   = tid & 63;
    const int fr  = l & 15;
    const int q   = l >> 4;

    // 512 blocks = 8 xcd * (32 m-pairs * 2 n); siblings adjacent on one XCD
    const int bid   = blockIdx.x;
    const int xcd   = bid & 7;
    const int idx   = bid >> 3;
    const int mt    = xcd * 32 + (idx >> 1);
    const int ntile = idx & 1;
    const int m0    = mt * 64;
    const int n0    = ntile * 256;

    // x staging: thread -> (row ar, cols hc..hc+3), swizzled f16 LDS layout
    const int ar = tid >> 3;
    const int hc = (tid & 7) * 4;
    const int abyte = ((((hc >> 3) ^ ((ar >> 1) & 3)) << 4) | ((hc << 1) & 15));
    const float* xrow = x + (size_t)(m0 + ar) * F_ + hc;

    #define ISSUE_B(t, buf)                                                   \
    {                                                                         \
        const _Float16* ck_ = btK + (size_t)(t) * (512 * 32) + n0 * 32;       \
        gl_lds16(ck_ + w * 1024 + l * 8,       &Bs[buf][w * 1024]);           \
        gl_lds16(ck_ + w * 1024 + 512 + l * 8, &Bs[buf][w * 1024 + 512]);     \
    }

    #define LOADX(t) (*reinterpret_cast<const float4*>(xrow + (size_t)(t) * 32))

    #define WRITE_A(v, buf)                                                   \
    {                                                                         \
        f16x4 hh; hh[0] = (_Float16)v.x; hh[1] = (_Float16)v.y;               \
        hh[2] = (_Float16)v.z; hh[3] = (_Float16)v.w;                         \
        *reinterpret_cast<f16x4*>(                                            \
            reinterpret_cast<char*>(&As[buf][0]) + ar * 64 + abyte) = hh;     \
    }

    #define COMPUTE(buf)                                                      \
    {                                                                         \
        f16x8 af[4], bf[2];                                                   \
        _Pragma("unroll")                                                     \
        for (int i = 0; i < 4; ++i) {                                         \
            int r   = i * 16 + fr;                                            \
            int off = r * 64 + ((q ^ ((r >> 1) & 3)) << 4);                   \
            af[i] = *reinterpret_cast<const f16x8*>(                          \
                reinterpret_cast<const char*>(&As[buf][0]) + off);            \
        }                                                                     \
        _Pragma("unroll")                                                     \
        for (int j = 0; j < 2; ++j) {                                         \
            int n   = w * 32 + j * 16 + fr;                                   \
            int off = n * 64 + ((q ^ ((n >> 1) & 3)) << 4);                   \
            bf[j] = *reinterpret_cast<const f16x8*>(                          \
                reinterpret_cast<const char*>(&Bs[buf][0]) + off);            \
        }                                                                     \
        _Pragma("unroll")                                                     \
        for (int i = 0; i < 4; ++i)                                           \
            _Pragma("unroll")                                                 \
            for (int j = 0; j < 2; ++j)                                       \
                acc[i][j] = __builtin_amdgcn_mfma_f32_16x16x32_f16(           \
                    af[i], bf[j], acc[i][j], 0, 0, 0);                        \
    }

    f32x4 acc[4][2] = {};
    float4 xvA, xvB;

    ISSUE_B(0, 0) xvA = LOADX(0);
    ISSUE_B(1, 1) xvB = LOADX(1);
    WRITE_A(xvA, 0)
    lds_barrier();                       // As[0]/Bs[0] ready (x(0) wait retired B(0))

    int b0 = 0, b1 = 1, b2 = 2;
    for (int t = 0; t < KSTEPS; t += 2) {
        if (t + 2 < KSTEPS) { ISSUE_B(t + 2, b2) xvA = LOADX(t + 2); }
        if (t + 1 < KSTEPS) WRITE_A(xvB, b1)     // waits x(t+1) -> B(t+1),B(t) done
        COMPUTE(b0)
        lds_barrier();
        if (t + 3 < KSTEPS) { ISSUE_B(t + 3, b0) xvB = LOADX(t + 3); }
        if (t + 2 < KSTEPS) WRITE_A(xvA, b2)
        COMPUTE(b1)
        lds_barrier();
        int tmp = b2; b2 = b1; b1 = b0; b0 = tmp;   // (b0,b1,b2) <- (b2,b0,b1)
    }
    #undef ISSUE_B
    #undef LOADX
    #undef WRITE_A
    #undef COMPUTE

    #pragma unroll
    for (int j = 0; j < 2; ++j) {
        const int nn = n0 + w * 32 + j * 16 + fr;
        const int ch = (nn & 127) * 4 + (nn >> 7);   // gate-interleaved channel
        const float bj = bias[nn];
        #pragma unroll
        for (int i = 0; i < 4; ++i)
            #pragma unroll
            for (int r = 0; r < 4; ++r)
                z[(size_t)(m0 + i * 16 + q * 4 + r) * G4H + ch]
                    = acc[i][j][r] + bj;
    }
}

// ---------------------------------------------------------------------------
// Kernel 2: MFMA LSTM recurrence — R17: 4 waves (256 thr), each wave owns 32
// channels (2 column tiles), 32 MFMA/step/wave. Halves the post-barrier LDS
// read burst (16 vs 32 ds_read_b128) and the barrier width (4 vs 8 waves).
// hL stash + 32-step copyout REMOVED: q==0 lanes store h straight to global
// (fire-and-forget; nothing reads hs until dense_out). Arithmetic per channel
// is bit-identical to R7/R16 (same fragments, same summation order).
// ---------------------------------------------------------------------------
__device__ __forceinline__ float sig_f(float x) {
    return 1.0f / (1.0f + __expf(-x));
}
__device__ __forceinline__ float tanh_f(float x) {
    return 1.0f - 2.0f / (__expf(2.0f * x) + 1.0f);
}

__global__ __launch_bounds__(256, 1) void lstm_mfma(
    const float* __restrict__ z,       // [B*T, H, 4] gate-interleaved
    const _Float16* __restrict__ wrT,  // [4H, H] = Wr^T fp16
    float* __restrict__ hs)            // [B, T, H] fp32
{
    const int b    = blockIdx.x;
    const int tid  = threadIdx.x;
    const int w    = tid >> 6;         // 0..3
    const int lane = tid & 63;
    const int l15  = lane & 15;
    const int q    = lane >> 4;
    const int jj0  = w * 32 + l15;     // first owned channel
    const int jj1  = jj0 + 16;         // second owned channel

    __shared__ __align__(16) _Float16 hA[2][128];   // 512 B double-buffered h

    // B operands: [col-tile][gate][kf] — 32 x f16x8 = 128 VGPR, loaded once.
    f16x8 bf0[4][4], bf1[4][4];
    #pragma unroll
    for (int g = 0; g < 4; ++g)
        #pragma unroll
        for (int kf = 0; kf < 4; ++kf) {
            bf0[g][kf] = *reinterpret_cast<const f16x8*>(
                &wrT[(size_t)(g * H_ + jj0) * H_ + kf * 32 + q * 8]);
            bf1[g][kf] = *reinterpret_cast<const f16x8*>(
                &wrT[(size_t)(g * H_ + jj1) * H_ + kf * 32 + q * 8]);
        }

    float cs0 = 0.f, cs1 = 0.f;
    if (tid < 128) reinterpret_cast<unsigned int*>(hA)[tid] = 0u;

    const float* zrA = z + (size_t)b * T_ * G4H + jj0 * 4;
    const float* zrB = z + (size_t)b * T_ * G4H + jj1 * 4;
    float*       hbase = hs + (size_t)b * T_ * H_;

    const f32x4 zero4 = {0.f, 0.f, 0.f, 0.f};

    float4 zA0 = *reinterpret_cast<const float4*>(zrA + (size_t)0 * G4H);
    float4 zB0 = *reinterpret_cast<const float4*>(zrB + (size_t)0 * G4H);
    float4 zA1 = *reinterpret_cast<const float4*>(zrA + (size_t)1 * G4H);
    float4 zB1 = *reinterpret_cast<const float4*>(zrB + (size_t)1 * G4H);

    __syncthreads();

    #define LSTM_STEP(t, ZA, ZB)                                              \
    {                                                                         \
        const int cur = (t) & 1;                                              \
        f16x8 af0 = *reinterpret_cast<const f16x8*>(&hA[cur][0 * 32 + q * 8]);\
        f16x8 af1 = *reinterpret_cast<const f16x8*>(&hA[cur][1 * 32 + q * 8]);\
        f16x8 af2 = *reinterpret_cast<const f16x8*>(&hA[cur][2 * 32 + q * 8]);\
        f16x8 af3 = *reinterpret_cast<const f16x8*>(&hA[cur][3 * 32 + q * 8]);\
        float za0_ = ZA.x, za1_ = ZA.y, za2_ = ZA.z, za3_ = ZA.w;             \
        float zb0_ = ZB.x, zb1_ = ZB.y, zb2_ = ZB.z, zb3_ = ZB.w;             \
        ZA = *reinterpret_cast<const float4*>(                                \
            zrA + (size_t)(((t) + 2) & (T_ - 1)) * G4H);                      \
        ZB = *reinterpret_cast<const float4*>(                                \
            zrB + (size_t)(((t) + 2) & (T_ - 1)) * G4H);                      \
        float g0v[4], g1v[4];                                                 \
        _Pragma("unroll")                                                     \
        for (int g = 0; g < 4; ++g) {                                         \
            f32x4 aA = __builtin_amdgcn_mfma_f32_16x16x32_f16(                \
                af0, bf0[g][0], zero4, 0, 0, 0);                              \
            aA = __builtin_amdgcn_mfma_f32_16x16x32_f16(                      \
                af1, bf0[g][1], aA, 0, 0, 0);                                 \
            f32x4 aB = __builtin_amdgcn_mfma_f32_16x16x32_f16(                \
                af2, bf0[g][2], zero4, 0, 0, 0);                              \
            aB = __builtin_amdgcn_mfma_f32_16x16x32_f16(                      \
                af3, bf0[g][3], aB, 0, 0, 0);                                 \
            g0v[g] = aA[0] + aB[0];                                           \
        }                                                                     \
        _Pragma("unroll")                                                     \
        for (int g = 0; g < 4; ++g) {                                         \
            f32x4 aA = __builtin_amdgcn_mfma_f32_16x16x32_f16(                \
                af0, bf1[g][0], zero4, 0, 0, 0);                              \
            aA = __builtin_amdgcn_mfma_f32_16x16x32_f16(                      \
                af1, bf1[g][1], aA, 0, 0, 0);                                 \
            f32x4 aB = __builtin_amdgcn_mfma_f32_16x16x32_f16(                \
                af2, bf1[g][2], zero4, 0, 0, 0);                              \
            aB = __builtin_amdgcn_mfma_f32_16x16x32_f16(                      \
                af3, bf1[g][3], aB, 0, 0, 0);                                 \
            g1v[g] = aA[0] + aB[0];                                           \
        }                                                                     \
        float i0 = sig_f(g0v[0] + za0_);                                      \
        float f0 = sig_f(g0v[1] + za1_);                                      \
        float c0 = tanh_f(g0v[2] + za2_);                                     \
        float o0 = sig_f(g0v[3] + za3_);                                      \
        cs0 = f0 * cs0 + i0 * c0;                                             \
        float h0 = o0 * tanh_f(cs0);                                          \
        float i1 = sig_f(g1v[0] + zb0_);                                      \
        float f1 = sig_f(g1v[1] + zb1_);                                      \
        float c1 = tanh_f(g1v[2] + zb2_);                                     \
        float o1 = sig_f(g1v[3] + zb3_);                                      \
        cs1 = f1 * cs1 + i1 * c1;                                             \
        float h1 = o1 * tanh_f(cs1);                                          \
        if (q == 0) {                                                         \
            hA[cur ^ 1][jj0] = (_Float16)h0;                                  \
            hA[cur ^ 1][jj1] = (_Float16)h1;                                  \
            hbase[(size_t)(t) * H_ + jj0] = h0;                               \
            hbase[(size_t)(t) * H_ + jj1] = h1;                               \
        }                                                                     \
        lds_barrier();                                                        \
    }

    for (int t = 0; t < T_; t += 2) {
        LSTM_STEP(t,     zA0, zB0)
        LSTM_STEP(t + 1, zA1, zB1)
    }
    #undef LSTM_STEP
}

// ---------------------------------------------------------------------------
// Kernel 3: out = hs @ Wd + bd
// ---------------------------------------------------------------------------
__global__ __launch_bounds__(256) void dense_out(
    const float* __restrict__ hs, const float* __restrict__ Wd,
    const float* __restrict__ bd, float* __restrict__ out)
{
    int idx = blockIdx.x * 256 + threadIdx.x;
    if (idx >= B_ * T_ * NCLS) return;
    int cls = idx % NCLS;
    int row = idx / NCLS;
    const float* h = hs + (size_t)row * H_;
    float acc = bd[cls];
    #pragma unroll 8
    for (int k = 0; k < H_; ++k) acc += h[k] * Wd[k * NCLS + cls];
    out[idx] = acc;
}

// ---------------------------------------------------------------------------
extern "C" void kernel_launch(void* const* d_in, const int* in_sizes, int n_in,
                              void* d_out, int out_size, void* d_ws, size_t ws_size,
                              hipStream_t stream)
{
    const float* x  = (const float*)d_in[0];
    const float* Wk = (const float*)d_in[1];
    const float* Wr = (const float*)d_in[2];
    const float* b  = (const float*)d_in[3];
    const float* Wd = (const float*)d_in[4];
    const float* bd = (const float*)d_in[5];
    float* out = (float*)d_out;

    float*     z   = (float*)d_ws;                       // [M, H, 4] fp32
    float*     hs  = z + (size_t)M_ * G4H;               // [M, H]  fp32
    _Float16*  btK = (_Float16*)(hs + (size_t)M_ * H_);  // k-major swizzled, 4 MB
    _Float16*  wrT = btK + (size_t)G4H * F_;             // [4H, H] fp16

    cvt_wkT<<<dim3(F_ / 64, G4H / 64), 256, 0, stream>>>(Wk, btK);
    cvt_wrT<<<dim3(H_ / 64, G4H / 64), 256, 0, stream>>>(Wr, wrT);
    gemm_fused<<<512, 512, 0, stream>>>(x, btK, b, z);
    lstm_mfma<<<B_, 256, 0, stream>>>(z, wrT, hs);
    int total = B_ * T_ * NCLS;
    dense_out<<<(total + 255) / 256, 256, 0, stream>>>(hs, Wd, bd, out);
}

// Round 3
// 368.867 us; speedup vs baseline: 1.3655x; 1.3655x over previous
//
#include <hip/hip_runtime.h>
#include <hip/hip_bf16.h>
#include <hip/hip_fp16.h>
#include <math.h>

// Problem dims (fixed by reference)
#define B_  32
#define T_  512
#define F_  4096
#define H_  128
#define G4H 512           // 4*H
#define NCLS 3            // NUM_CLASSES + 1
#define M_  (B_ * T_)     // 16384 rows
#define KSTEPS 128        // F_/32

typedef _Float16 f16x8 __attribute__((ext_vector_type(8)));
typedef _Float16 f16x4 __attribute__((ext_vector_type(4)));
typedef float    f32x4 __attribute__((ext_vector_type(4)));

// async global->LDS, 16B per lane; LDS dest is wave-uniform base + lane*16
__device__ __forceinline__ void gl_lds16(const _Float16* g, _Float16* l) {
    __builtin_amdgcn_global_load_lds(
        (const __attribute__((address_space(1))) void*)(g),
        (__attribute__((address_space(3))) void*)(l), 16, 0, 0);
}

// ---------------------------------------------------------------------------
// Kernel 0b: Wk [F,4H] fp32 -> btK fp16, K-MAJOR tiles with baked-in group
// swizzle: group g (8 halves) of column n stored at half-offset
//   n*32 + ((g ^ ((n>>1)&3)) << 3)
// so gemm's ds_read_b128 B-fragment reads are bank-conflict-free (2-way).
// ---------------------------------------------------------------------------
__global__ __launch_bounds__(256) void cvt_wkT(
    const float* __restrict__ Wk, _Float16* __restrict__ btK)
{
    __shared__ float ls[64][65];
    const int k0 = blockIdx.x * 64;
    const int n0 = blockIdx.y * 64;
    const int tid = threadIdx.x;

    {
        int r  = tid >> 4;
        int c4 = (tid & 15) * 4;
        #pragma unroll
        for (int p = 0; p < 4; ++p) {
            float4 v = *reinterpret_cast<const float4*>(
                &Wk[(size_t)(k0 + r + p * 16) * G4H + n0 + c4]);
            ls[r + p * 16][c4 + 0] = v.x;
            ls[r + p * 16][c4 + 1] = v.y;
            ls[r + p * 16][c4 + 2] = v.z;
            ls[r + p * 16][c4 + 3] = v.w;
        }
    }
    __syncthreads();
    {
        int rn = tid >> 2;            // n within tile 0..63
        int ck = (tid & 3) * 16;      // k within tile 0,16,32,48
        f16x8 h0, h1;
        #pragma unroll
        for (int j = 0; j < 8; ++j) {
            h0[j] = (_Float16)ls[ck + j][rn];
            h1[j] = (_Float16)ls[ck + 8 + j][rn];
        }
        const int n    = n0 + rn;
        const int kg   = k0 + ck;
        const int kblk = kg >> 5;
        const int kk   = kg & 31;           // 0 or 16
        const int g0   = kk >> 3;           // 0 or 2
        const int sw   = (n >> 1) & 3;
        _Float16* base = btK + (size_t)kblk * (512 * 32) + (size_t)n * 32;
        *reinterpret_cast<f16x8*>(base + ((g0 ^ sw) << 3))       = h0;
        *reinterpret_cast<f16x8*>(base + (((g0 + 1) ^ sw) << 3)) = h1;
    }
}

// ---------------------------------------------------------------------------
// Kernel 0c: Wr [H,4H] fp32 -> wrT [4H,H] fp16 (transpose). grid (2, 8).
// ---------------------------------------------------------------------------
__global__ __launch_bounds__(256) void cvt_wrT(
    const float* __restrict__ Wr, _Float16* __restrict__ wrT)
{
    __shared__ float ls[64][65];
    const int k0 = blockIdx.x * 64;
    const int n0 = blockIdx.y * 64;
    const int tid = threadIdx.x;
    {
        int r  = tid >> 4;
        int c4 = (tid & 15) * 4;
        #pragma unroll
        for (int p = 0; p < 4; ++p) {
            float4 v = *reinterpret_cast<const float4*>(
                &Wr[(size_t)(k0 + r + p * 16) * G4H + n0 + c4]);
            ls[r + p * 16][c4 + 0] = v.x;
            ls[r + p * 16][c4 + 1] = v.y;
            ls[r + p * 16][c4 + 2] = v.z;
            ls[r + p * 16][c4 + 3] = v.w;
        }
    }
    __syncthreads();
    {
        int rn = tid >> 2;
        int ck = (tid & 3) * 16;
        f16x8 h0, h1;
        #pragma unroll
        for (int j = 0; j < 8; ++j) {
            h0[j] = (_Float16)ls[ck + j][rn];
            h1[j] = (_Float16)ls[ck + 8 + j][rn];
        }
        _Float16* dst = &wrT[(size_t)(n0 + rn) * H_ + k0 + ck];
        *reinterpret_cast<f16x8*>(dst)     = h0;
        *reinterpret_cast<f16x8*>(dst + 8) = h1;
    }
}

// Light producer-consumer barrier: LDS-drain only, no vmcnt drain.
__device__ __forceinline__ void lds_barrier() {
    asm volatile("s_waitcnt lgkmcnt(0)" ::: "memory");
    __builtin_amdgcn_s_barrier();
    asm volatile("" ::: "memory");
}

// ---------------------------------------------------------------------------
// Kernel 1: FUSED z = f16(x) @ Wk + b. (unchanged)
// ---------------------------------------------------------------------------
__global__ __launch_bounds__(512, 4) void gemm_fused(
    const float* __restrict__ x, const _Float16* __restrict__ btK,
    const float* __restrict__ bias, float* __restrict__ z)
{
    __shared__ __align__(16) _Float16 As[3][64 * 32];    // 12 KB
    __shared__ __align__(16) _Float16 Bs[3][256 * 32];   // 48 KB

    const int tid = threadIdx.x;
    const int w   = tid >> 6;
    const int l   = tid & 63;
    const int fr  = l & 15;
    const int q   = l >> 4;

    // 512 blocks = 8 xcd * (32 m-pairs * 2 n); siblings adjacent on one XCD
    const int bid   = blockIdx.x;
    const int xcd   = bid & 7;
    const int idx   = bid >> 3;
    const int mt    = xcd * 32 + (idx >> 1);
    const int ntile = idx & 1;
    const int m0    = mt * 64;
    const int n0    = ntile * 256;

    // x staging: thread -> (row ar, cols hc..hc+3), swizzled f16 LDS layout
    const int ar = tid >> 3;
    const int hc = (tid & 7) * 4;
    const int abyte = ((((hc >> 3) ^ ((ar >> 1) & 3)) << 4) | ((hc << 1) & 15));
    const float* xrow = x + (size_t)(m0 + ar) * F_ + hc;

    #define ISSUE_B(t, buf)                                                   \
    {                                                                         \
        const _Float16* ck_ = btK + (size_t)(t) * (512 * 32) + n0 * 32;       \
        gl_lds16(ck_ + w * 1024 + l * 8,       &Bs[buf][w * 1024]);           \
        gl_lds16(ck_ + w * 1024 + 512 + l * 8, &Bs[buf][w * 1024 + 512]);     \
    }

    #define LOADX(t) (*reinterpret_cast<const float4*>(xrow + (size_t)(t) * 32))

    #define WRITE_A(v, buf)                                                   \
    {                                                                         \
        f16x4 hh; hh[0] = (_Float16)v.x; hh[1] = (_Float16)v.y;               \
        hh[2] = (_Float16)v.z; hh[3] = (_Float16)v.w;                         \
        *reinterpret_cast<f16x4*>(                                            \
            reinterpret_cast<char*>(&As[buf][0]) + ar * 64 + abyte) = hh;     \
    }

    #define COMPUTE(buf)                                                      \
    {                                                                         \
        f16x8 af[4], bf[2];                                                   \
        _Pragma("unroll")                                                     \
        for (int i = 0; i < 4; ++i) {                                         \
            int r   = i * 16 + fr;                                            \
            int off = r * 64 + ((q ^ ((r >> 1) & 3)) << 4);                   \
            af[i] = *reinterpret_cast<const f16x8*>(                          \
                reinterpret_cast<const char*>(&As[buf][0]) + off);            \
        }                                                                     \
        _Pragma("unroll")                                                     \
        for (int j = 0; j < 2; ++j) {                                         \
            int n   = w * 32 + j * 16 + fr;                                   \
            int off = n * 64 + ((q ^ ((n >> 1) & 3)) << 4);                   \
            bf[j] = *reinterpret_cast<const f16x8*>(                          \
                reinterpret_cast<const char*>(&Bs[buf][0]) + off);            \
        }                                                                     \
        _Pragma("unroll")                                                     \
        for (int i = 0; i < 4; ++i)                                           \
            _Pragma("unroll")                                                 \
            for (int j = 0; j < 2; ++j)                                       \
                acc[i][j] = __builtin_amdgcn_mfma_f32_16x16x32_f16(           \
                    af[i], bf[j], acc[i][j], 0, 0, 0);                        \
    }

    f32x4 acc[4][2] = {};
    float4 xvA, xvB;

    ISSUE_B(0, 0) xvA = LOADX(0);
    ISSUE_B(1, 1) xvB = LOADX(1);
    WRITE_A(xvA, 0)
    lds_barrier();                       // As[0]/Bs[0] ready (x(0) wait retired B(0))

    int b0 = 0, b1 = 1, b2 = 2;
    for (int t = 0; t < KSTEPS; t += 2) {
        if (t + 2 < KSTEPS) { ISSUE_B(t + 2, b2) xvA = LOADX(t + 2); }
        if (t + 1 < KSTEPS) WRITE_A(xvB, b1)     // waits x(t+1) -> B(t+1),B(t) done
        COMPUTE(b0)
        lds_barrier();
        if (t + 3 < KSTEPS) { ISSUE_B(t + 3, b0) xvB = LOADX(t + 3); }
        if (t + 2 < KSTEPS) WRITE_A(xvA, b2)
        COMPUTE(b1)
        lds_barrier();
        int tmp = b2; b2 = b1; b1 = b0; b0 = tmp;   // (b0,b1,b2) <- (b2,b0,b1)
    }
    #undef ISSUE_B
    #undef LOADX
    #undef WRITE_A
    #undef COMPUTE

    #pragma unroll
    for (int j = 0; j < 2; ++j) {
        const int nn = n0 + w * 32 + j * 16 + fr;
        const int ch = (nn & 127) * 4 + (nn >> 7);   // gate-interleaved channel
        const float bj = bias[nn];
        #pragma unroll
        for (int i = 0; i < 4; ++i)
            #pragma unroll
            for (int r = 0; r < 4; ++r)
                z[(size_t)(m0 + i * 16 + q * 4 + r) * G4H + ch]
                    = acc[i][j][r] + bj;
    }
}

// ---------------------------------------------------------------------------
// Kernel 2: MFMA LSTM recurrence — R18: back to the 8-wave R16 structure
// (post-mortem: gate math is wave-wide, so 4 waves doubled per-wave VALU
// issue; active-CU VALUBusy was ~60% => VALU-issue-bound). Changes vs R16:
//  - gates via raw v_exp/v_rcp (4-5 ops vs ~20 for exact-div path)
//  - h stored straight to global (no hL stash, no periodic vmcnt drain)
//  - unroll x4 with compile-time cur; int-only address math
// MFMA fragments/summation order identical to R16.
// ---------------------------------------------------------------------------
__device__ __forceinline__ float sig_f(float x) {
    return __builtin_amdgcn_rcpf(
        1.0f + __builtin_amdgcn_exp2f(-1.442695040888963f * x));
}
__device__ __forceinline__ float tanh_f(float x) {
    return 1.0f - 2.0f * __builtin_amdgcn_rcpf(
        1.0f + __builtin_amdgcn_exp2f(2.885390081777927f * x));
}

__global__ __launch_bounds__(512, 2) void lstm_mfma(
    const float* __restrict__ z,       // [B*T, H, 4] gate-interleaved
    const _Float16* __restrict__ wrT,  // [4H, H] = Wr^T fp16
    float* __restrict__ hs)            // [B, T, H] fp32
{
    const int b    = blockIdx.x;
    const int tid  = threadIdx.x;
    const int w    = tid >> 6;
    const int lane = tid & 63;
    const int l15  = lane & 15;
    const int q    = lane >> 4;
    const int jj   = w * 16 + l15;

    __shared__ __align__(16) _Float16 hA[2][128];

    f16x8 bf[4][4];
    #pragma unroll
    for (int g = 0; g < 4; ++g)
        #pragma unroll
        for (int kf = 0; kf < 4; ++kf)
            bf[g][kf] = *reinterpret_cast<const f16x8*>(
                &wrT[(size_t)(g * H_ + jj) * H_ + kf * 32 + q * 8]);

    float cstate = 0.f;
    if (tid < 128) reinterpret_cast<unsigned int*>(hA)[tid] = 0u;

    const float* zrow  = z  + (size_t)b * T_ * G4H + jj * 4;
    float*       hbase = hs + (size_t)b * T_ * H_;

    const f32x4 zero4 = {0.f, 0.f, 0.f, 0.f};

    float4 zP0 = *reinterpret_cast<const float4*>(zrow + (size_t)(0 << 9));
    float4 zP1 = *reinterpret_cast<const float4*>(zrow + (size_t)(1 << 9));
    float4 zP2 = *reinterpret_cast<const float4*>(zrow + (size_t)(2 << 9));
    float4 zP3 = *reinterpret_cast<const float4*>(zrow + (size_t)(3 << 9));

    __syncthreads();

    #define LSTM_STEP(t, CUR, ZZ)                                             \
    {                                                                         \
        f16x8 af0 = *reinterpret_cast<const f16x8*>(&hA[CUR][0 * 32 + q * 8]);\
        f16x8 af1 = *reinterpret_cast<const f16x8*>(&hA[CUR][1 * 32 + q * 8]);\
        f16x8 af2 = *reinterpret_cast<const f16x8*>(&hA[CUR][2 * 32 + q * 8]);\
        f16x8 af3 = *reinterpret_cast<const f16x8*>(&hA[CUR][3 * 32 + q * 8]);\
        float zt0_ = ZZ.x, zt1_ = ZZ.y, zt2_ = ZZ.z, zt3_ = ZZ.w;             \
        ZZ = *reinterpret_cast<const float4*>(                                \
            zrow + (size_t)((((t) + 4) & (T_ - 1)) << 9));                    \
        float gv[4];                                                          \
        _Pragma("unroll")                                                     \
        for (int g = 0; g < 4; ++g) {                                         \
            f32x4 aA = __builtin_amdgcn_mfma_f32_16x16x32_f16(                \
                af0, bf[g][0], zero4, 0, 0, 0);                               \
            aA = __builtin_amdgcn_mfma_f32_16x16x32_f16(                      \
                af1, bf[g][1], aA, 0, 0, 0);                                  \
            f32x4 aB = __builtin_amdgcn_mfma_f32_16x16x32_f16(                \
                af2, bf[g][2], zero4, 0, 0, 0);                               \
            aB = __builtin_amdgcn_mfma_f32_16x16x32_f16(                      \
                af3, bf[g][3], aB, 0, 0, 0);                                  \
            gv[g] = aA[0] + aB[0];                                           \
        }                                                                     \
        float iv = sig_f(gv[0] + zt0_);                                       \
        float fv = sig_f(gv[1] + zt1_);                                       \
        float cc = tanh_f(gv[2] + zt2_);                                      \
        float ov = sig_f(gv[3] + zt3_);                                       \
        cstate = fv * cstate + iv * cc;                                       \
        float h = ov * tanh_f(cstate);                                        \
        if (q == 0) {                                                         \
            hA[CUR ^ 1][jj] = (_Float16)h;                                    \
            hbase[((t) << 7) + jj] = h;                                       \
        }                                                                     \
        lds_barrier();                                                        \
    }

    for (int t = 0; t < T_; t += 4) {
        LSTM_STEP(t,     0, zP0)
        LSTM_STEP(t + 1, 1, zP1)
        LSTM_STEP(t + 2, 0, zP2)
        LSTM_STEP(t + 3, 1, zP3)
    }
    #undef LSTM_STEP
}

// ---------------------------------------------------------------------------
// Kernel 3: out = hs @ Wd + bd
// ---------------------------------------------------------------------------
__global__ __launch_bounds__(256) void dense_out(
    const float* __restrict__ hs, const float* __restrict__ Wd,
    const float* __restrict__ bd, float* __restrict__ out)
{
    int idx = blockIdx.x * 256 + threadIdx.x;
    if (idx >= B_ * T_ * NCLS) return;
    int cls = idx % NCLS;
    int row = idx / NCLS;
    const float* h = hs + (size_t)row * H_;
    float acc = bd[cls];
    #pragma unroll 8
    for (int k = 0; k < H_; ++k) acc += h[k] * Wd[k * NCLS + cls];
    out[idx] = acc;
}

// ---------------------------------------------------------------------------
extern "C" void kernel_launch(void* const* d_in, const int* in_sizes, int n_in,
                              void* d_out, int out_size, void* d_ws, size_t ws_size,
                              hipStream_t stream)
{
    const float* x  = (const float*)d_in[0];
    const float* Wk = (const float*)d_in[1];
    const float* Wr = (const float*)d_in[2];
    const float* b  = (const float*)d_in[3];
    const float* Wd = (const float*)d_in[4];
    const float* bd = (const float*)d_in[5];
    float* out = (float*)d_out;

    float*     z   = (float*)d_ws;                       // [M, H, 4] fp32
    float*     hs  = z + (size_t)M_ * G4H;               // [M, H]  fp32
    _Float16*  btK = (_Float16*)(hs + (size_t)M_ * H_);  // k-major swizzled, 4 MB
    _Float16*  wrT = btK + (size_t)G4H * F_;             // [4H, H] fp16

    cvt_wkT<<<dim3(F_ / 64, G4H / 64), 256, 0, stream>>>(Wk, btK);
    cvt_wrT<<<dim3(H_ / 64, G4H / 64), 256, 0, stream>>>(Wr, wrT);
    gemm_fused<<<512, 512, 0, stream>>>(x, btK, b, z);
    lstm_mfma<<<B_, 512, 0, stream>>>(z, wrT, hs);
    int total = B_ * T_ * NCLS;
    dense_out<<<(total + 255) / 256, 256, 0, stream>>>(hs, Wd, bd, out);
}